// Round 2
// baseline (664.021 us; speedup 1.0000x reference)
//
#include <hip/hip_runtime.h>
#include <stdint.h>

// Problem constants
#define B_   2
#define S_   2048      // SQ == SK
#define H_   1024
#define NH_  16
#define D_   64
#define KC_  3072      // KS*H = conv GEMM K-dim

typedef __attribute__((ext_vector_type(8))) short  short8;   // 8 x bf16 bits (4 VGPRs)
typedef __attribute__((ext_vector_type(4))) float  floatx4;  // MFMA C/D

__device__ __forceinline__ unsigned short f2bf(float f) {
    union { float f; unsigned u; } v; v.f = f;
    unsigned r = v.u + 0x7fffu + ((v.u >> 16) & 1u);   // RNE
    return (unsigned short)(r >> 16);
}

// ---------------------------------------------------------------------------
// 1) x [B,2048,1024] f32  ->  xpad [B,2050,1024] bf16 with zero rows at 0,2049
// ---------------------------------------------------------------------------
__global__ __launch_bounds__(256) void k_pad_convert(const float* __restrict__ src,
                                                     unsigned short* __restrict__ dst) {
    int gid = blockIdx.x * 256 + threadIdx.x;
    int vid = gid * 4;
    if (vid >= B_ * 2050 * 1024) return;
    int row = vid >> 10;
    int b   = (row >= 2050) ? 1 : 0;
    int r   = row - b * 2050;
    int h   = vid & 1023;
    unsigned short o0 = 0, o1 = 0, o2 = 0, o3 = 0;
    if (r != 0 && r != 2049) {
        const float4 f = *(const float4*)(src + ((b * 2048 + r - 1) << 10) + h);
        o0 = f2bf(f.x); o1 = f2bf(f.y); o2 = f2bf(f.z); o3 = f2bf(f.w);
    }
    ushort4 o; o.x = o0; o.y = o1; o.z = o2; o.w = o3;
    *(ushort4*)(dst + vid) = o;
}

// ---------------------------------------------------------------------------
// 2) W [R][C] f32 -> Wt [C][R] bf16
// ---------------------------------------------------------------------------
__global__ void k_transpose_bf16(const float* __restrict__ src,
                                 unsigned short* __restrict__ dst, int R, int C) {
    __shared__ float t[32][33];
    int c0 = blockIdx.x * 32, r0 = blockIdx.y * 32;
    int tx = threadIdx.x, ty = threadIdx.y;           // (32,8)
#pragma unroll
    for (int k = 0; k < 4; ++k)
        t[ty + k * 8][tx] = src[(long)(r0 + ty + k * 8) * C + c0 + tx];
    __syncthreads();
#pragma unroll
    for (int k = 0; k < 4; ++k)
        dst[(long)(c0 + ty + k * 8) * R + r0 + tx] = f2bf(t[tx][ty + k * 8]);
}

// ---------------------------------------------------------------------------
// 3) Conv-as-GEMM with register-prefetch pipeline.
//    M=4096, K=3072, N=1024, tile 128x128, BK=64, 256 threads.
//    Per iter: ds_write(tile k) ; bar ; global->reg load(tile k+1) overlapped
//    with ds_read+MFMA(tile k) ; bar.  (No global_load_lds: its LDS-write
//    side forces vmcnt(0) drain at the barrier; reg loads overlap compute.)
// ---------------------------------------------------------------------------
__global__ __launch_bounds__(256) void k_conv_gemm(
    const unsigned short* __restrict__ xq, const unsigned short* __restrict__ xs,
    const unsigned short* __restrict__ Wqt, const unsigned short* __restrict__ Wkt,
    const unsigned short* __restrict__ Wvt,
    const float* __restrict__ bq, const float* __restrict__ bk, const float* __restrict__ bv,
    unsigned short* __restrict__ Qo, unsigned short* __restrict__ Ko,
    unsigned short* __restrict__ Vo) {
    int z = blockIdx.z;
    const unsigned short* X = (z == 0) ? xq : xs;
    const unsigned short* W = (z == 0) ? Wqt : (z == 1 ? Wkt : Wvt);
    const float* bias = (z == 0) ? bq : (z == 1 ? bk : bv);

    __shared__ unsigned short Al[128 * 64];
    __shared__ unsigned short Bl[128 * 64];

    int n0 = blockIdx.x * 128, m0 = blockIdx.y * 128;
    int b = m0 >> 11;
    int tid = threadIdx.x, lane = tid & 63, w = tid >> 6;
    int quad = lane >> 4, l15 = lane & 15;
    int wm = w >> 1, wn = w & 1;

    floatx4 acc[4][4];
#pragma unroll
    for (int i = 0; i < 4; ++i)
#pragma unroll
        for (int j = 0; j < 4; ++j) acc[i][j] = (floatx4){0.f, 0.f, 0.f, 0.f};

    int arow0 = (m0 + 2 * b) * 1024;

    // per-thread staging slots (lane-linear LDS, XOR-swizzled source chunk)
    int eoff[4], aoff[4], boff[4];
#pragma unroll
    for (int it = 0; it < 4; ++it) {
        int e  = (it * 256 + tid) * 8;
        int rl = e >> 6;
        int cp = (e >> 3) & 7;
        int c  = cp ^ (rl & 7);
        eoff[it] = e;
        aoff[it] = arow0 + rl * 1024 + c * 8;
        boff[it] = (n0 + rl) * KC_ + c * 8;
    }

    int4 ra[4], rb[4];
#pragma unroll
    for (int it = 0; it < 4; ++it) {
        ra[it] = *(const int4*)(X + aoff[it]);
        rb[it] = *(const int4*)(W + boff[it]);
    }

    for (int kt = 0; kt < 48; ++kt) {
#pragma unroll
        for (int it = 0; it < 4; ++it) {
            *(int4*)((char*)Al + eoff[it] * 2) = ra[it];
            *(int4*)((char*)Bl + eoff[it] * 2) = rb[it];
        }
        __syncthreads();
        if (kt + 1 < 48) {
            int k0 = (kt + 1) * 64;
#pragma unroll
            for (int it = 0; it < 4; ++it) {
                ra[it] = *(const int4*)(X + aoff[it] + k0);
                rb[it] = *(const int4*)(W + boff[it] + k0);
            }
        }
#pragma unroll
        for (int kk = 0; kk < 2; ++kk) {
            short8 af[4], bf[4];
#pragma unroll
            for (int i = 0; i < 4; ++i) {
                int m  = wm * 64 + i * 16 + l15;
                int cp = (kk * 4 + quad) ^ (m & 7);
                af[i]  = *(const short8*)(Al + m * 64 + cp * 8);
            }
#pragma unroll
            for (int j = 0; j < 4; ++j) {
                int n  = wn * 64 + j * 16 + l15;
                int cp = (kk * 4 + quad) ^ (n & 7);
                bf[j]  = *(const short8*)(Bl + n * 64 + cp * 8);
            }
#pragma unroll
            for (int i = 0; i < 4; ++i)
#pragma unroll
                for (int j = 0; j < 4; ++j)
                    acc[i][j] = __builtin_amdgcn_mfma_f32_16x16x32_bf16(af[i], bf[j], acc[i][j], 0, 0, 0);
        }
        __syncthreads();
    }

    // epilogue: C/D layout col=lane&15, row=quad*4+reg
#pragma unroll
    for (int j = 0; j < 4; ++j) {
        int n = n0 + wn * 64 + j * 16 + l15;
        float bb = bias[n];
        int nh = n >> 6, d = n & 63;
#pragma unroll
        for (int i = 0; i < 4; ++i) {
            int srow = (m0 & 2047) + wm * 64 + i * 16 + quad * 4;
#pragma unroll
            for (int r = 0; r < 4; ++r) {
                float v = acc[i][j][r] + bb;
                int s = srow + r;
                if (z == 0)
                    Qo[((b * NH_ + nh) * 2048 + s) * 64 + d] = f2bf(v * 0.125f);
                else if (z == 1)
                    Ko[((b * NH_ + nh) * 2048 + s) * 64 + d] = f2bf(v);
                else
                    Vo[((b * NH_ + nh) * 64 + d) * 2048 + s] = f2bf(v);
            }
        }
    }
}

// ---------------------------------------------------------------------------
// 4) Flash attention, 512 threads (8 waves, 16 q-rows each), reg-prefetch K/V.
//    LDS: Ul = union{K-tile 128x64 swizzled, P 128x136 bf16}, Vl 64x128.
// ---------------------------------------------------------------------------
__global__ __launch_bounds__(512) void k_flash(
    const unsigned short* __restrict__ Q, const unsigned short* __restrict__ K,
    const unsigned short* __restrict__ Vt, const float* __restrict__ mask,
    unsigned short* __restrict__ Ao) {
    __shared__ unsigned short Ul[128 * 136];   // 34816 B
    __shared__ unsigned short Vl[64 * 128];    // 16384 B

    int tid = threadIdx.x, w = tid >> 6, lane = tid & 63;
    int quad = lane >> 4, l15 = lane & 15;
    int bh = blockIdx.y;
    int b = bh >> 4, nh = bh & 15;
    int q0 = blockIdx.x * 128, wq = w * 16;

    // Q fragments (A-layout: m=lane&15, k=quad*8+j)
    short8 qf[2];
#pragma unroll
    for (int kk = 0; kk < 2; ++kk)
        qf[kk] = *(const short8*)(Q + ((bh * 2048 + q0 + wq + l15) << 6) + kk * 32 + quad * 8);

    floatx4 oacc[4];
    float rsum[4];
#pragma unroll
    for (int j = 0; j < 4; ++j) oacc[j] = (floatx4){0.f, 0.f, 0.f, 0.f};
#pragma unroll
    for (int r = 0; r < 4; ++r) rsum[r] = 0.f;
    const float* maskb = mask + b * S_;

    // staging slots (512 threads: 2 x 16B chunks each for K and V)
    int ek[2], kof[2], vof[2];
#pragma unroll
    for (int it = 0; it < 2; ++it) {
        int e  = (it * 512 + tid) * 8;
        ek[it] = e;
        int kl = e >> 6;
        int c  = ((e >> 3) & 7) ^ (kl & 7);
        kof[it] = (bh * 2048 + kl) * 64 + c * 8;
        int dl = e >> 7;
        int cp = (e >> 3) & 15;
        int c2 = (cp & 8) | ((cp ^ dl) & 7);
        vof[it] = (bh * 64 + dl) * 2048 + c2 * 8;
    }

    int4 rk[2], rv[2];
#pragma unroll
    for (int it = 0; it < 2; ++it) {
        rk[it] = *(const int4*)(K + kof[it]);          // K: +k0*64 per tile row step
        rv[it] = *(const int4*)(Vt + vof[it]);
    }

    for (int kt = 0; kt < 16; ++kt) {
        int k0 = kt * 128;
#pragma unroll
        for (int it = 0; it < 2; ++it) {
            *(int4*)((char*)Ul + ek[it] * 2) = rk[it];
            *(int4*)((char*)Vl + ek[it] * 2) = rv[it];
        }
        __syncthreads();
        if (kt < 15) {
            int kn = (kt + 1) * 128;
#pragma unroll
            for (int it = 0; it < 2; ++it) {
                rk[it] = *(const int4*)(K + kof[it] + kn * 64);
                rv[it] = *(const int4*)(Vt + vof[it] + kn);
            }
        }

        // S = Q K^T  (wave: 16 q-rows x 128 keys)
        floatx4 sacc[8];
#pragma unroll
        for (int j = 0; j < 8; ++j) sacc[j] = (floatx4){0.f, 0.f, 0.f, 0.f};
#pragma unroll
        for (int j = 0; j < 8; ++j) {
            int kl = j * 16 + l15;
            int cp0 = (0 * 4 + quad) ^ (kl & 7);
            short8 bf0 = *(const short8*)(Ul + kl * 64 + cp0 * 8);
            int cp1 = (1 * 4 + quad) ^ (kl & 7);
            short8 bf1 = *(const short8*)(Ul + kl * 64 + cp1 * 8);
            sacc[j] = __builtin_amdgcn_mfma_f32_16x16x32_bf16(qf[0], bf0, sacc[j], 0, 0, 0);
            sacc[j] = __builtin_amdgcn_mfma_f32_16x16x32_bf16(qf[1], bf1, sacc[j], 0, 0, 0);
        }
        __syncthreads();   // all waves done reading K-tile before P overwrites Ul

        // P = exp(S + mask*-1e9); write own 16 rows, pitch 136
#pragma unroll
        for (int j = 0; j < 8; ++j) {
            float mv = maskb[k0 + j * 16 + l15] * (-1e9f);
            int row = wq + quad * 4;
#pragma unroll
            for (int r = 0; r < 4; ++r) {
                float p = __expf(sacc[j][r] + mv);
                rsum[r] += p;
                Ul[(row + r) * 136 + j * 16 + l15] = f2bf(p);
            }
        }
        // no barrier: each wave reads only its own P rows (in-wave LDS order)

        // O += P V
#pragma unroll
        for (int kk = 0; kk < 4; ++kk) {
            short8 af = *(const short8*)(Ul + (wq + l15) * 136 + kk * 32 + quad * 8);
            short8 bv4[4];
#pragma unroll
            for (int j2 = 0; j2 < 4; ++j2) {
                int dl = j2 * 16 + l15;
                int c  = kk * 4 + quad;
                int cp = (c & 8) | ((c ^ dl) & 7);
                bv4[j2] = *(const short8*)(Vl + dl * 128 + cp * 8);
            }
#pragma unroll
            for (int j2 = 0; j2 < 4; ++j2)
                oacc[j2] = __builtin_amdgcn_mfma_f32_16x16x32_bf16(af, bv4[j2], oacc[j2], 0, 0, 0);
        }
        __syncthreads();   // before next iter restages Ul/Vl
    }

    // row sums: reduce across the 16 lanes of each quad
#pragma unroll
    for (int r = 0; r < 4; ++r) {
        float v = rsum[r];
        v += __shfl_xor(v, 1); v += __shfl_xor(v, 2);
        v += __shfl_xor(v, 4); v += __shfl_xor(v, 8);
        rsum[r] = 1.0f / v;
    }

#pragma unroll
    for (int j2 = 0; j2 < 4; ++j2)
#pragma unroll
        for (int r = 0; r < 4; ++r) {
            int qrow = q0 + wq + quad * 4 + r;
            int hcol = nh * 64 + j2 * 16 + l15;
            Ao[(b * 2048 + qrow) * 1024 + hcol] = f2bf(oacc[j2][r] * rsum[r]);
        }
}

// ---------------------------------------------------------------------------
// 5) Output projection: tile 64x128, reg-prefetch pipeline, 512 blocks (2/CU).
// ---------------------------------------------------------------------------
__global__ __launch_bounds__(256) void k_proj_gemm(
    const unsigned short* __restrict__ A, const unsigned short* __restrict__ Wt,
    const float* __restrict__ bo, float* __restrict__ out) {
    __shared__ unsigned short Al[64 * 64];
    __shared__ unsigned short Bl[128 * 64];

    int n0 = blockIdx.x * 128, m0 = blockIdx.y * 64;
    int tid = threadIdx.x, lane = tid & 63, w = tid >> 6;
    int quad = lane >> 4, l15 = lane & 15;
    int wm = w >> 1, wn = w & 1;

    floatx4 acc[2][4];
#pragma unroll
    for (int i = 0; i < 2; ++i)
#pragma unroll
        for (int j = 0; j < 4; ++j) acc[i][j] = (floatx4){0.f, 0.f, 0.f, 0.f};

    int ea[2], ao[2], eb[4], bo_[4];
#pragma unroll
    for (int it = 0; it < 2; ++it) {
        int e  = (it * 256 + tid) * 8;
        int rl = e >> 6;
        int c  = ((e >> 3) & 7) ^ (rl & 7);
        ea[it] = e;
        ao[it] = (m0 + rl) * 1024 + c * 8;
    }
#pragma unroll
    for (int it = 0; it < 4; ++it) {
        int e  = (it * 256 + tid) * 8;
        int rl = e >> 6;
        int c  = ((e >> 3) & 7) ^ (rl & 7);
        eb[it] = e;
        bo_[it] = (n0 + rl) * 1024 + c * 8;
    }

    int4 ra[2], rb[4];
#pragma unroll
    for (int it = 0; it < 2; ++it) ra[it] = *(const int4*)(A + ao[it]);
#pragma unroll
    for (int it = 0; it < 4; ++it) rb[it] = *(const int4*)(Wt + bo_[it]);

    for (int kt = 0; kt < 16; ++kt) {
#pragma unroll
        for (int it = 0; it < 2; ++it) *(int4*)((char*)Al + ea[it] * 2) = ra[it];
#pragma unroll
        for (int it = 0; it < 4; ++it) *(int4*)((char*)Bl + eb[it] * 2) = rb[it];
        __syncthreads();
        if (kt + 1 < 16) {
            int k0 = (kt + 1) * 64;
#pragma unroll
            for (int it = 0; it < 2; ++it) ra[it] = *(const int4*)(A + ao[it] + k0);
#pragma unroll
            for (int it = 0; it < 4; ++it) rb[it] = *(const int4*)(Wt + bo_[it] + k0);
        }
#pragma unroll
        for (int kk = 0; kk < 2; ++kk) {
            short8 af[2], bf[4];
#pragma unroll
            for (int i = 0; i < 2; ++i) {
                int m  = wm * 32 + i * 16 + l15;
                int cp = (kk * 4 + quad) ^ (m & 7);
                af[i]  = *(const short8*)(Al + m * 64 + cp * 8);
            }
#pragma unroll
            for (int j = 0; j < 4; ++j) {
                int n  = wn * 64 + j * 16 + l15;
                int cp = (kk * 4 + quad) ^ (n & 7);
                bf[j]  = *(const short8*)(Bl + n * 64 + cp * 8);
            }
#pragma unroll
            for (int i = 0; i < 2; ++i)
#pragma unroll
                for (int j = 0; j < 4; ++j)
                    acc[i][j] = __builtin_amdgcn_mfma_f32_16x16x32_bf16(af[i], bf[j], acc[i][j], 0, 0, 0);
        }
        __syncthreads();
    }

#pragma unroll
    for (int j = 0; j < 4; ++j) {
        int n = n0 + wn * 64 + j * 16 + l15;
        float bb = bo[n];
#pragma unroll
        for (int i = 0; i < 2; ++i) {
            int m = m0 + wm * 32 + i * 16 + quad * 4;
#pragma unroll
            for (int r = 0; r < 4; ++r)
                out[(m + r) * 1024 + n] = acc[i][j][r] + bb;
        }
    }
}

// ---------------------------------------------------------------------------
extern "C" void kernel_launch(void* const* d_in, const int* in_sizes, int n_in,
                              void* d_out, int out_size, void* d_ws, size_t ws_size,
                              hipStream_t stream) {
    (void)in_sizes; (void)n_in; (void)out_size; (void)ws_size;
    const float* q_in = (const float*)d_in[0];
    const float* s_in = (const float*)d_in[1];
    const float* mask = (const float*)d_in[2];
    const float* Wq   = (const float*)d_in[3];
    const float* bq   = (const float*)d_in[4];
    const float* Wk   = (const float*)d_in[5];
    const float* bk   = (const float*)d_in[6];
    const float* Wv   = (const float*)d_in[7];
    const float* bv   = (const float*)d_in[8];
    const float* Wo   = (const float*)d_in[9];
    const float* bo   = (const float*)d_in[10];
    float* out = (float*)d_out;

    char* ws = (char*)d_ws;
    size_t off = 0;
    auto alloc = [&](size_t bytes) {
        char* p = ws + off;
        off += (bytes + 255) & ~(size_t)255;
        return p;
    };
    unsigned short* xqp = (unsigned short*)alloc((size_t)B_ * 2050 * 1024 * 2);
    unsigned short* xsp = (unsigned short*)alloc((size_t)B_ * 2050 * 1024 * 2);
    unsigned short* Wqt = (unsigned short*)alloc((size_t)KC_ * H_ * 2);
    unsigned short* Wkt = (unsigned short*)alloc((size_t)KC_ * H_ * 2);
    unsigned short* Wvt = (unsigned short*)alloc((size_t)KC_ * H_ * 2);
    unsigned short* Wot = (unsigned short*)alloc((size_t)H_ * H_ * 2);
    unsigned short* Qb  = (unsigned short*)alloc((size_t)B_ * NH_ * S_ * D_ * 2);
    unsigned short* Kb  = (unsigned short*)alloc((size_t)B_ * NH_ * S_ * D_ * 2);
    unsigned short* Vtb = (unsigned short*)alloc((size_t)B_ * NH_ * S_ * D_ * 2);
    unsigned short* Ab  = (unsigned short*)alloc((size_t)B_ * S_ * H_ * 2);

    k_pad_convert<<<4100, 256, 0, stream>>>(q_in, xqp);
    k_pad_convert<<<4100, 256, 0, stream>>>(s_in, xsp);
    k_transpose_bf16<<<dim3(32, 96), dim3(32, 8), 0, stream>>>(Wq, Wqt, KC_, H_);
    k_transpose_bf16<<<dim3(32, 96), dim3(32, 8), 0, stream>>>(Wk, Wkt, KC_, H_);
    k_transpose_bf16<<<dim3(32, 96), dim3(32, 8), 0, stream>>>(Wv, Wvt, KC_, H_);
    k_transpose_bf16<<<dim3(32, 32), dim3(32, 8), 0, stream>>>(Wo, Wot, H_, H_);
    k_conv_gemm<<<dim3(8, 32, 3), 256, 0, stream>>>(xqp, xsp, Wqt, Wkt, Wvt,
                                                    bq, bk, bv, Qb, Kb, Vtb);
    k_flash<<<dim3(16, 32), 512, 0, stream>>>(Qb, Kb, Vtb, mask, Ab);
    k_proj_gemm<<<dim3(8, 64), 256, 0, stream>>>(Ab, Wot, bo, out);
}

// Round 3
// 361.324 us; speedup vs baseline: 1.8377x; 1.8377x over previous
//
#include <hip/hip_runtime.h>
#include <stdint.h>

// Problem constants
#define B_   2
#define S_   2048      // SQ == SK
#define H_   1024
#define NH_  16
#define D_   64
#define KC_  3072      // KS*H = conv GEMM K-dim

typedef __attribute__((ext_vector_type(8))) short  short8;   // 8 x bf16 bits (4 VGPRs)
typedef __attribute__((ext_vector_type(4))) float  floatx4;  // MFMA C/D

typedef __attribute__((address_space(1))) const void gas_void;
typedef __attribute__((address_space(3))) void       las_void;

// async 16B global->LDS; LDS dest must be wave-uniform base + lane*16.
__device__ __forceinline__ void gld16(const void* g, void* l) {
    __builtin_amdgcn_global_load_lds((gas_void*)g, (las_void*)l, 16, 0, 0);
}

__device__ __forceinline__ unsigned short f2bf(float f) {
    union { float f; unsigned u; } v; v.f = f;
    unsigned r = v.u + 0x7fffu + ((v.u >> 16) & 1u);   // RNE
    return (unsigned short)(r >> 16);
}

// ---------------------------------------------------------------------------
// 1) x [B,2048,1024] f32  ->  xpad [B,2050,1024] bf16 with zero rows at 0,2049
// ---------------------------------------------------------------------------
__global__ __launch_bounds__(256) void k_pad_convert(const float* __restrict__ src,
                                                     unsigned short* __restrict__ dst) {
    int gid = blockIdx.x * 256 + threadIdx.x;
    int vid = gid * 4;
    if (vid >= B_ * 2050 * 1024) return;
    int row = vid >> 10;
    int b   = (row >= 2050) ? 1 : 0;
    int r   = row - b * 2050;
    int h   = vid & 1023;
    unsigned short o0 = 0, o1 = 0, o2 = 0, o3 = 0;
    if (r != 0 && r != 2049) {
        const float4 f = *(const float4*)(src + ((b * 2048 + r - 1) << 10) + h);
        o0 = f2bf(f.x); o1 = f2bf(f.y); o2 = f2bf(f.z); o3 = f2bf(f.w);
    }
    ushort4 o; o.x = o0; o.y = o1; o.z = o2; o.w = o3;
    *(ushort4*)(dst + vid) = o;
}

// ---------------------------------------------------------------------------
// 2) W [R][C] f32 -> Wt [C][R] bf16
// ---------------------------------------------------------------------------
__global__ void k_transpose_bf16(const float* __restrict__ src,
                                 unsigned short* __restrict__ dst, int R, int C) {
    __shared__ float t[32][33];
    int c0 = blockIdx.x * 32, r0 = blockIdx.y * 32;
    int tx = threadIdx.x, ty = threadIdx.y;           // (32,8)
#pragma unroll
    for (int k = 0; k < 4; ++k)
        t[ty + k * 8][tx] = src[(long)(r0 + ty + k * 8) * C + c0 + tx];
    __syncthreads();
#pragma unroll
    for (int k = 0; k < 4; ++k)
        dst[(long)(c0 + ty + k * 8) * R + r0 + tx] = f2bf(t[tx][ty + k * 8]);
}

// ---------------------------------------------------------------------------
// 3) Conv-as-GEMM, LDS double-buffered global_load_lds pipeline.
//    M=4096, K=3072, N=1024, tile 128x128, BK=64, 256 threads, 64 KB LDS.
//    Per iter: issue gld16(next tile -> other buffer); ds_read+MFMA(current);
//    barrier. The in-flight loads overlap the whole compute phase, so the
//    vmcnt(0) drain at the barrier is mostly hidden. No data held in VGPRs
//    across the barrier (round-2's reg-prefetch spilled to scratch: +634 MB
//    WRITE_SIZE — never again).
// ---------------------------------------------------------------------------
__global__ __launch_bounds__(256) void k_conv_gemm(
    const unsigned short* __restrict__ xq, const unsigned short* __restrict__ xs,
    const unsigned short* __restrict__ Wqt, const unsigned short* __restrict__ Wkt,
    const unsigned short* __restrict__ Wvt,
    const float* __restrict__ bq, const float* __restrict__ bk, const float* __restrict__ bv,
    unsigned short* __restrict__ Qo, unsigned short* __restrict__ Ko,
    unsigned short* __restrict__ Vo) {
    int z = blockIdx.z;
    const unsigned short* X = (z == 0) ? xq : xs;
    const unsigned short* W = (z == 0) ? Wqt : (z == 1 ? Wkt : Wvt);
    const float* bias = (z == 0) ? bq : (z == 1 ? bk : bv);

    __shared__ unsigned short Al[2][128 * 64];
    __shared__ unsigned short Bl[2][128 * 64];

    int n0 = blockIdx.x * 128, m0 = blockIdx.y * 128;
    int b = m0 >> 11;
    int tid = threadIdx.x, lane = tid & 63, w = tid >> 6;
    int quad = lane >> 4, l15 = lane & 15;
    int wm = w >> 1, wn = w & 1;

    floatx4 acc[4][4];
#pragma unroll
    for (int i = 0; i < 4; ++i)
#pragma unroll
        for (int j = 0; j < 4; ++j) acc[i][j] = (floatx4){0.f, 0.f, 0.f, 0.f};

    int arow0 = (m0 + 2 * b) * 1024;

    // per-thread staging slots (lane-linear LDS dest, XOR-swizzled source chunk)
    int eoff[4], aoff[4], boff[4];
#pragma unroll
    for (int it = 0; it < 4; ++it) {
        int e  = (it * 256 + tid) * 8;
        int rl = e >> 6;
        int cp = (e >> 3) & 7;
        int c  = cp ^ (rl & 7);
        eoff[it] = e;
        aoff[it] = arow0 + rl * 1024 + c * 8;
        boff[it] = (n0 + rl) * KC_ + c * 8;
    }

    auto stage = [&](int buf, int k0) {
#pragma unroll
        for (int it = 0; it < 4; ++it) {
            gld16(X + aoff[it] + k0, (char*)Al[buf] + eoff[it] * 2);
            gld16(W + boff[it] + k0, (char*)Bl[buf] + eoff[it] * 2);
        }
    };
    auto compute = [&](int buf) {
#pragma unroll
        for (int kk = 0; kk < 2; ++kk) {
            short8 af[4], bf[4];
#pragma unroll
            for (int i = 0; i < 4; ++i) {
                int m  = wm * 64 + i * 16 + l15;
                int cp = (kk * 4 + quad) ^ (m & 7);
                af[i]  = *(const short8*)(Al[buf] + m * 64 + cp * 8);
            }
#pragma unroll
            for (int j = 0; j < 4; ++j) {
                int n  = wn * 64 + j * 16 + l15;
                int cp = (kk * 4 + quad) ^ (n & 7);
                bf[j]  = *(const short8*)(Bl[buf] + n * 64 + cp * 8);
            }
#pragma unroll
            for (int i = 0; i < 4; ++i)
#pragma unroll
                for (int j = 0; j < 4; ++j)
                    acc[i][j] = __builtin_amdgcn_mfma_f32_16x16x32_bf16(af[i], bf[j], acc[i][j], 0, 0, 0);
        }
    };

    stage(0, 0);
    __syncthreads();
    for (int kt = 0; kt < 48; kt += 2) {
        if (kt + 1 < 48) stage(1, (kt + 1) * 64);
        compute(0);
        __syncthreads();
        if (kt + 2 < 48) stage(0, (kt + 2) * 64);
        compute(1);
        __syncthreads();
    }

    // epilogue: C/D layout col=lane&15, row=quad*4+reg
#pragma unroll
    for (int j = 0; j < 4; ++j) {
        int n = n0 + wn * 64 + j * 16 + l15;
        float bb = bias[n];
        int nh = n >> 6, d = n & 63;
#pragma unroll
        for (int i = 0; i < 4; ++i) {
            int srow = (m0 & 2047) + wm * 64 + i * 16 + quad * 4;
#pragma unroll
            for (int r = 0; r < 4; ++r) {
                float v = acc[i][j][r] + bb;
                int s = srow + r;
                if (z == 0)
                    Qo[((b * NH_ + nh) * 2048 + s) * 64 + d] = f2bf(v * 0.125f);
                else if (z == 1)
                    Ko[((b * NH_ + nh) * 2048 + s) * 64 + d] = f2bf(v);
                else
                    Vo[((b * NH_ + nh) * 64 + d) * 2048 + s] = f2bf(v);
            }
        }
    }
}

// ---------------------------------------------------------------------------
// 4) Flash attention (round-1 known-good version).
//    Block: 128 q-rows (4 waves x 32), one (b,nh); loop 16 key-tiles of 128.
//    LDS: Ul = union{ K-tile 128x64 swizzled, P 128x136 bf16 }, Vl 64x128.
// ---------------------------------------------------------------------------
__global__ __launch_bounds__(256) void k_flash(
    const unsigned short* __restrict__ Q, const unsigned short* __restrict__ K,
    const unsigned short* __restrict__ Vt, const float* __restrict__ mask,
    unsigned short* __restrict__ Ao) {
    __shared__ unsigned short Ul[128 * 136];   // 34816 B
    __shared__ unsigned short Vl[64 * 128];    // 16384 B

    int tid = threadIdx.x, w = tid >> 6, lane = tid & 63;
    int quad = lane >> 4, l15 = lane & 15;
    int bh = blockIdx.y;
    int b = bh >> 4, nh = bh & 15;
    int q0 = blockIdx.x * 128, wq = w * 32;

    short8 qf[2][2];
#pragma unroll
    for (int i = 0; i < 2; ++i)
#pragma unroll
        for (int kk = 0; kk < 2; ++kk)
            qf[i][kk] = *(const short8*)(Q + ((bh * 2048 + q0 + wq + i * 16 + l15) << 6) + kk * 32 + quad * 8);

    floatx4 oacc[2][4];
    float rsum[2][4];
#pragma unroll
    for (int i = 0; i < 2; ++i) {
#pragma unroll
        for (int j = 0; j < 4; ++j) oacc[i][j] = (floatx4){0.f, 0.f, 0.f, 0.f};
#pragma unroll
        for (int r = 0; r < 4; ++r) rsum[i][r] = 0.f;
    }
    const float* maskb = mask + b * S_;

    for (int kt = 0; kt < 16; ++kt) {
        int k0 = kt * 128;
#pragma unroll
        for (int it = 0; it < 4; ++it) {
            int e  = (it * 256 + tid) * 8;
            int kl = e >> 6;
            int c  = ((e >> 3) & 7) ^ (kl & 7);
            gld16(K + (bh * 2048 + k0 + kl) * 64 + c * 8, (char*)Ul + e * 2);
            int dl = e >> 7;
            int cp = (e >> 3) & 15;
            int c2 = (cp & 8) | ((cp ^ dl) & 7);
            gld16(Vt + (bh * 64 + dl) * 2048 + k0 + c2 * 8, (char*)Vl + e * 2);
        }
        __syncthreads();

        // S = Q K^T  (wave: 32 q-rows x 128 keys)
        floatx4 sacc[2][8];
#pragma unroll
        for (int i = 0; i < 2; ++i)
#pragma unroll
            for (int j = 0; j < 8; ++j) sacc[i][j] = (floatx4){0.f, 0.f, 0.f, 0.f};
#pragma unroll
        for (int j = 0; j < 8; ++j) {
            int kl = j * 16 + l15;
            int cp0 = (0 * 4 + quad) ^ (kl & 7);
            short8 bf0 = *(const short8*)(Ul + kl * 64 + cp0 * 8);
            int cp1 = (1 * 4 + quad) ^ (kl & 7);
            short8 bf1 = *(const short8*)(Ul + kl * 64 + cp1 * 8);
#pragma unroll
            for (int i = 0; i < 2; ++i) {
                sacc[i][j] = __builtin_amdgcn_mfma_f32_16x16x32_bf16(qf[i][0], bf0, sacc[i][j], 0, 0, 0);
                sacc[i][j] = __builtin_amdgcn_mfma_f32_16x16x32_bf16(qf[i][1], bf1, sacc[i][j], 0, 0, 0);
            }
        }
        __syncthreads();   // all waves done reading K-tile before P overwrites Ul

        // P = exp(S + mask*-1e9)
#pragma unroll
        for (int j = 0; j < 8; ++j) {
            float mv = maskb[k0 + j * 16 + l15] * (-1e9f);
#pragma unroll
            for (int i = 0; i < 2; ++i) {
                int row = wq + i * 16 + quad * 4;
#pragma unroll
                for (int r = 0; r < 4; ++r) {
                    float p = __expf(sacc[i][j][r] + mv);
                    rsum[i][r] += p;
                    Ul[(row + r) * 136 + j * 16 + l15] = f2bf(p);
                }
            }
        }
        // no barrier: each wave reads only its own P rows

        // O += P V
#pragma unroll
        for (int kk = 0; kk < 4; ++kk) {
            short8 af[2], bv4[4];
#pragma unroll
            for (int i = 0; i < 2; ++i)
                af[i] = *(const short8*)(Ul + (wq + i * 16 + l15) * 136 + kk * 32 + quad * 8);
#pragma unroll
            for (int j2 = 0; j2 < 4; ++j2) {
                int dl = j2 * 16 + l15;
                int c  = kk * 4 + quad;
                int cp = (c & 8) | ((c ^ dl) & 7);
                bv4[j2] = *(const short8*)(Vl + dl * 128 + cp * 8);
            }
#pragma unroll
            for (int i = 0; i < 2; ++i)
#pragma unroll
                for (int j2 = 0; j2 < 4; ++j2)
                    oacc[i][j2] = __builtin_amdgcn_mfma_f32_16x16x32_bf16(af[i], bv4[j2], oacc[i][j2], 0, 0, 0);
        }
        __syncthreads();
    }

#pragma unroll
    for (int i = 0; i < 2; ++i)
#pragma unroll
        for (int r = 0; r < 4; ++r) {
            float v = rsum[i][r];
            v += __shfl_xor(v, 1); v += __shfl_xor(v, 2);
            v += __shfl_xor(v, 4); v += __shfl_xor(v, 8);
            rsum[i][r] = 1.0f / v;
        }

#pragma unroll
    for (int i = 0; i < 2; ++i)
#pragma unroll
        for (int j2 = 0; j2 < 4; ++j2)
#pragma unroll
            for (int r = 0; r < 4; ++r) {
                int qrow = q0 + wq + i * 16 + quad * 4 + r;
                int hcol = nh * 64 + j2 * 16 + l15;
                Ao[(b * 2048 + qrow) * 1024 + hcol] = f2bf(oacc[i][j2][r] * rsum[i][r]);
            }
}

// ---------------------------------------------------------------------------
// 5) Output projection, same double-buffered pipeline. Tile 128x128, K=1024.
// ---------------------------------------------------------------------------
__global__ __launch_bounds__(256) void k_proj_gemm(
    const unsigned short* __restrict__ A, const unsigned short* __restrict__ Wt,
    const float* __restrict__ bo, float* __restrict__ out) {
    __shared__ unsigned short Al[2][128 * 64];
    __shared__ unsigned short Bl[2][128 * 64];

    int n0 = blockIdx.x * 128, m0 = blockIdx.y * 128;
    int tid = threadIdx.x, lane = tid & 63, w = tid >> 6;
    int quad = lane >> 4, l15 = lane & 15;
    int wm = w >> 1, wn = w & 1;

    floatx4 acc[4][4];
#pragma unroll
    for (int i = 0; i < 4; ++i)
#pragma unroll
        for (int j = 0; j < 4; ++j) acc[i][j] = (floatx4){0.f, 0.f, 0.f, 0.f};

    int eoff[4], aoff[4], boff[4];
#pragma unroll
    for (int it = 0; it < 4; ++it) {
        int e  = (it * 256 + tid) * 8;
        int rl = e >> 6;
        int c  = ((e >> 3) & 7) ^ (rl & 7);
        eoff[it] = e;
        aoff[it] = (m0 + rl) * 1024 + c * 8;
        boff[it] = (n0 + rl) * 1024 + c * 8;
    }

    auto stage = [&](int buf, int k0) {
#pragma unroll
        for (int it = 0; it < 4; ++it) {
            gld16(A + aoff[it] + k0, (char*)Al[buf] + eoff[it] * 2);
            gld16(Wt + boff[it] + k0, (char*)Bl[buf] + eoff[it] * 2);
        }
    };
    auto compute = [&](int buf) {
#pragma unroll
        for (int kk = 0; kk < 2; ++kk) {
            short8 af[4], bf[4];
#pragma unroll
            for (int i = 0; i < 4; ++i) {
                int m  = wm * 64 + i * 16 + l15;
                int cp = (kk * 4 + quad) ^ (m & 7);
                af[i]  = *(const short8*)(Al[buf] + m * 64 + cp * 8);
            }
#pragma unroll
            for (int j = 0; j < 4; ++j) {
                int n  = wn * 64 + j * 16 + l15;
                int cp = (kk * 4 + quad) ^ (n & 7);
                bf[j]  = *(const short8*)(Bl[buf] + n * 64 + cp * 8);
            }
#pragma unroll
            for (int i = 0; i < 4; ++i)
#pragma unroll
                for (int j = 0; j < 4; ++j)
                    acc[i][j] = __builtin_amdgcn_mfma_f32_16x16x32_bf16(af[i], bf[j], acc[i][j], 0, 0, 0);
        }
    };

    stage(0, 0);
    __syncthreads();
    for (int kt = 0; kt < 16; kt += 2) {
        if (kt + 1 < 16) stage(1, (kt + 1) * 64);
        compute(0);
        __syncthreads();
        if (kt + 2 < 16) stage(0, (kt + 2) * 64);
        compute(1);
        __syncthreads();
    }

#pragma unroll
    for (int j = 0; j < 4; ++j) {
        int n = n0 + wn * 64 + j * 16 + l15;
        float bb = bo[n];
#pragma unroll
        for (int i = 0; i < 4; ++i) {
            int m = m0 + wm * 64 + i * 16 + quad * 4;
#pragma unroll
            for (int r = 0; r < 4; ++r)
                out[(m + r) * 1024 + n] = acc[i][j][r] + bb;
        }
    }
}

// ---------------------------------------------------------------------------
extern "C" void kernel_launch(void* const* d_in, const int* in_sizes, int n_in,
                              void* d_out, int out_size, void* d_ws, size_t ws_size,
                              hipStream_t stream) {
    (void)in_sizes; (void)n_in; (void)out_size; (void)ws_size;
    const float* q_in = (const float*)d_in[0];
    const float* s_in = (const float*)d_in[1];
    const float* mask = (const float*)d_in[2];
    const float* Wq   = (const float*)d_in[3];
    const float* bq   = (const float*)d_in[4];
    const float* Wk   = (const float*)d_in[5];
    const float* bk   = (const float*)d_in[6];
    const float* Wv   = (const float*)d_in[7];
    const float* bv   = (const float*)d_in[8];
    const float* Wo   = (const float*)d_in[9];
    const float* bo   = (const float*)d_in[10];
    float* out = (float*)d_out;

    char* ws = (char*)d_ws;
    size_t off = 0;
    auto alloc = [&](size_t bytes) {
        char* p = ws + off;
        off += (bytes + 255) & ~(size_t)255;
        return p;
    };
    unsigned short* xqp = (unsigned short*)alloc((size_t)B_ * 2050 * 1024 * 2);
    unsigned short* xsp = (unsigned short*)alloc((size_t)B_ * 2050 * 1024 * 2);
    unsigned short* Wqt = (unsigned short*)alloc((size_t)KC_ * H_ * 2);
    unsigned short* Wkt = (unsigned short*)alloc((size_t)KC_ * H_ * 2);
    unsigned short* Wvt = (unsigned short*)alloc((size_t)KC_ * H_ * 2);
    unsigned short* Wot = (unsigned short*)alloc((size_t)H_ * H_ * 2);
    unsigned short* Qb  = (unsigned short*)alloc((size_t)B_ * NH_ * S_ * D_ * 2);
    unsigned short* Kb  = (unsigned short*)alloc((size_t)B_ * NH_ * S_ * D_ * 2);
    unsigned short* Vtb = (unsigned short*)alloc((size_t)B_ * NH_ * S_ * D_ * 2);
    unsigned short* Ab  = (unsigned short*)alloc((size_t)B_ * S_ * H_ * 2);

    k_pad_convert<<<4100, 256, 0, stream>>>(q_in, xqp);
    k_pad_convert<<<4100, 256, 0, stream>>>(s_in, xsp);
    k_transpose_bf16<<<dim3(32, 96), dim3(32, 8), 0, stream>>>(Wq, Wqt, KC_, H_);
    k_transpose_bf16<<<dim3(32, 96), dim3(32, 8), 0, stream>>>(Wk, Wkt, KC_, H_);
    k_transpose_bf16<<<dim3(32, 96), dim3(32, 8), 0, stream>>>(Wv, Wvt, KC_, H_);
    k_transpose_bf16<<<dim3(32, 32), dim3(32, 8), 0, stream>>>(Wo, Wot, H_, H_);
    k_conv_gemm<<<dim3(8, 32, 3), 256, 0, stream>>>(xqp, xsp, Wqt, Wkt, Wvt,
                                                    bq, bk, bv, Qb, Kb, Vtb);
    k_flash<<<dim3(16, 32), 256, 0, stream>>>(Qb, Kb, Vtb, mask, Ab);
    k_proj_gemm<<<dim3(8, 32), 256, 0, stream>>>(Ab, Wot, bo, out);
}

// Round 4
// 316.885 us; speedup vs baseline: 2.0955x; 1.1402x over previous
//
#include <hip/hip_runtime.h>
#include <stdint.h>

// Problem constants
#define B_   2
#define S_   2048      // SQ == SK
#define H_   1024
#define NH_  16
#define D_   64
#define KC_  3072      // KS*H = conv GEMM K-dim

typedef __attribute__((ext_vector_type(8))) short  short8;   // 8 x bf16 bits (4 VGPRs)
typedef __attribute__((ext_vector_type(4))) float  floatx4;  // MFMA C/D

typedef __attribute__((address_space(1))) const void gas_void;
typedef __attribute__((address_space(3))) void       las_void;

// async 16B global->LDS; LDS dest must be wave-uniform base + lane*16.
__device__ __forceinline__ void gld16(const void* g, void* l) {
    __builtin_amdgcn_global_load_lds((gas_void*)g, (las_void*)l, 16, 0, 0);
}

__device__ __forceinline__ unsigned short f2bf(float f) {
    union { float f; unsigned u; } v; v.f = f;
    unsigned r = v.u + 0x7fffu + ((v.u >> 16) & 1u);   // RNE
    return (unsigned short)(r >> 16);
}

// ---------------------------------------------------------------------------
// 1) x [B,2048,1024] f32  ->  xpad [B,2050,1024] bf16 with zero rows at 0,2049
// ---------------------------------------------------------------------------
__global__ __launch_bounds__(256) void k_pad_convert(const float* __restrict__ src,
                                                     unsigned short* __restrict__ dst) {
    int gid = blockIdx.x * 256 + threadIdx.x;
    int vid = gid * 4;
    if (vid >= B_ * 2050 * 1024) return;
    int row = vid >> 10;
    int b   = (row >= 2050) ? 1 : 0;
    int r   = row - b * 2050;
    int h   = vid & 1023;
    unsigned short o0 = 0, o1 = 0, o2 = 0, o3 = 0;
    if (r != 0 && r != 2049) {
        const float4 f = *(const float4*)(src + ((b * 2048 + r - 1) << 10) + h);
        o0 = f2bf(f.x); o1 = f2bf(f.y); o2 = f2bf(f.z); o3 = f2bf(f.w);
    }
    ushort4 o; o.x = o0; o.y = o1; o.z = o2; o.w = o3;
    *(ushort4*)(dst + vid) = o;
}

// ---------------------------------------------------------------------------
// 2) W [R][C] f32 -> Wt [C][R] bf16
// ---------------------------------------------------------------------------
__global__ void k_transpose_bf16(const float* __restrict__ src,
                                 unsigned short* __restrict__ dst, int R, int C) {
    __shared__ float t[32][33];
    int c0 = blockIdx.x * 32, r0 = blockIdx.y * 32;
    int tx = threadIdx.x, ty = threadIdx.y;           // (32,8)
#pragma unroll
    for (int k = 0; k < 4; ++k)
        t[ty + k * 8][tx] = src[(long)(r0 + ty + k * 8) * C + c0 + tx];
    __syncthreads();
#pragma unroll
    for (int k = 0; k < 4; ++k)
        dst[(long)(c0 + ty + k * 8) * R + r0 + tx] = f2bf(t[tx][ty + k * 8]);
}

// ---------------------------------------------------------------------------
// 3) Conv-as-GEMM, SHIFT-DEDUPED: C[m][n] = sum_t sum_q X[m+t-1][q] Wt[n][t*1024+q]
//    Stage 130 X rows x 64 q-cols ONCE per iter (A for all 3 shifts: fragment
//    for shift t = staged row lm+t) + 3 shift-slices of W. 66 KB staged per
//    6.3 MFLOP (98 FLOP/B, was 64), 96 MFMA/wave per barrier (was 32),
//    16 K-iters (was 48). Addresses the measured 2.4 Kcyc/iter latency wall
//    that was invariant across R1/R2/R3 scheduling variants.
// ---------------------------------------------------------------------------
__global__ __launch_bounds__(256) void k_conv_gemm(
    const unsigned short* __restrict__ xq, const unsigned short* __restrict__ xs,
    const unsigned short* __restrict__ Wqt, const unsigned short* __restrict__ Wkt,
    const unsigned short* __restrict__ Wvt,
    const float* __restrict__ bq, const float* __restrict__ bk, const float* __restrict__ bv,
    unsigned short* __restrict__ Qo, unsigned short* __restrict__ Ko,
    unsigned short* __restrict__ Vo) {
    int z = blockIdx.z;
    const unsigned short* X = (z == 0) ? xq : xs;
    const unsigned short* W = (z == 0) ? Wqt : (z == 1 ? Wkt : Wvt);
    const float* bias = (z == 0) ? bq : (z == 1 ? bk : bv);

    __shared__ unsigned short Al[132 * 64];        // 130 rows used
    __shared__ unsigned short Bl[3 * 128 * 64];    // [t][n][k]

    int n0 = blockIdx.x * 128, m0 = blockIdx.y * 128;
    int b = m0 >> 11;
    int tid = threadIdx.x, lane = tid & 63, w = tid >> 6;
    int quad = lane >> 4, l15 = lane & 15;
    int wm = w >> 1, wn = w & 1;

    floatx4 acc[4][4];
#pragma unroll
    for (int i = 0; i < 4; ++i)
#pragma unroll
        for (int j = 0; j < 4; ++j) acc[i][j] = (floatx4){0.f, 0.f, 0.f, 0.f};

    // staged row r  <->  xpad row (m0 + 2b + r), r in [0,130)
    const unsigned short* Xbase = X + (m0 + 2 * b) * 1024;

    // A staging: 128 rows via 4x256 chunks, rows 128..129 via threads 0..15
    int eaA[4], oaA[4];
#pragma unroll
    for (int it = 0; it < 4; ++it) {
        int e  = (it * 256 + tid) * 8;
        int r  = e >> 6;
        int cp = (e >> 3) & 7;
        int c  = cp ^ (r & 7);
        eaA[it] = e;
        oaA[it] = r * 1024 + c * 8;
    }
    int eaX = 0, oaX = 0;             // extra rows 128,129 (16 chunks)
    if (tid < 16) {
        int e  = (1024 + tid) * 8;
        int r  = 128 + (tid >> 3);
        int cp = tid & 7;
        int c  = cp ^ (r & 7);
        eaX = e;
        oaX = r * 1024 + c * 8;
    }
    // B staging: 3 tiles x 128 rows x 8 chunks = 12x256 chunks
    int eaB[12], oaB[12];
#pragma unroll
    for (int it = 0; it < 12; ++it) {
        int e  = (it * 256 + tid) * 8;
        int t  = e >> 13;
        int er = e & 8191;
        int rl = er >> 6;
        int cp = (er >> 3) & 7;
        int c  = cp ^ (rl & 7);
        eaB[it] = e;
        oaB[it] = (n0 + rl) * KC_ + t * 1024 + c * 8;
    }

    for (int kt = 0; kt < 16; ++kt) {
        int k0 = kt * 64;
#pragma unroll
        for (int it = 0; it < 4; ++it)
            gld16(Xbase + oaA[it] + k0, (char*)Al + eaA[it] * 2);
        if (tid < 16)
            gld16(Xbase + oaX + k0, (char*)Al + eaX * 2);
#pragma unroll
        for (int it = 0; it < 12; ++it)
            gld16(W + oaB[it] + k0, (char*)Bl + eaB[it] * 2);
        __syncthreads();

#pragma unroll
        for (int t = 0; t < 3; ++t) {
#pragma unroll
            for (int kk = 0; kk < 2; ++kk) {
                short8 af[4], bf[4];
#pragma unroll
                for (int i = 0; i < 4; ++i) {
                    int r  = wm * 64 + i * 16 + l15 + t;      // shifted A row
                    int cp = (kk * 4 + quad) ^ (r & 7);
                    af[i]  = *(const short8*)(Al + r * 64 + cp * 8);
                }
#pragma unroll
                for (int j = 0; j < 4; ++j) {
                    int n  = wn * 64 + j * 16 + l15;
                    int cp = (kk * 4 + quad) ^ (n & 7);
                    bf[j]  = *(const short8*)(Bl + t * 8192 + n * 64 + cp * 8);
                }
#pragma unroll
                for (int i = 0; i < 4; ++i)
#pragma unroll
                    for (int j = 0; j < 4; ++j)
                        acc[i][j] = __builtin_amdgcn_mfma_f32_16x16x32_bf16(af[i], bf[j], acc[i][j], 0, 0, 0);
            }
        }
        __syncthreads();
    }

    // epilogue: C/D layout col=lane&15, row=quad*4+reg
#pragma unroll
    for (int j = 0; j < 4; ++j) {
        int n = n0 + wn * 64 + j * 16 + l15;
        float bb = bias[n];
        int nh = n >> 6, d = n & 63;
#pragma unroll
        for (int i = 0; i < 4; ++i) {
            int srow = (m0 & 2047) + wm * 64 + i * 16 + quad * 4;
#pragma unroll
            for (int r = 0; r < 4; ++r) {
                float v = acc[i][j][r] + bb;
                int s = srow + r;
                if (z == 0)
                    Qo[((b * NH_ + nh) * 2048 + s) * 64 + d] = f2bf(v * 0.125f);
                else if (z == 1)
                    Ko[((b * NH_ + nh) * 2048 + s) * 64 + d] = f2bf(v);
                else
                    Vo[((b * NH_ + nh) * 64 + d) * 2048 + s] = f2bf(v);
            }
        }
    }
}

// ---------------------------------------------------------------------------
// 4) Flash attention (known-good; untouched this round so it surfaces in the
//    profile with counters before optimizing).
// ---------------------------------------------------------------------------
__global__ __launch_bounds__(256) void k_flash(
    const unsigned short* __restrict__ Q, const unsigned short* __restrict__ K,
    const unsigned short* __restrict__ Vt, const float* __restrict__ mask,
    unsigned short* __restrict__ Ao) {
    __shared__ unsigned short Ul[128 * 136];   // 34816 B
    __shared__ unsigned short Vl[64 * 128];    // 16384 B

    int tid = threadIdx.x, w = tid >> 6, lane = tid & 63;
    int quad = lane >> 4, l15 = lane & 15;
    int bh = blockIdx.y;
    int b = bh >> 4, nh = bh & 15;
    int q0 = blockIdx.x * 128, wq = w * 32;

    short8 qf[2][2];
#pragma unroll
    for (int i = 0; i < 2; ++i)
#pragma unroll
        for (int kk = 0; kk < 2; ++kk)
            qf[i][kk] = *(const short8*)(Q + ((bh * 2048 + q0 + wq + i * 16 + l15) << 6) + kk * 32 + quad * 8);

    floatx4 oacc[2][4];
    float rsum[2][4];
#pragma unroll
    for (int i = 0; i < 2; ++i) {
#pragma unroll
        for (int j = 0; j < 4; ++j) oacc[i][j] = (floatx4){0.f, 0.f, 0.f, 0.f};
#pragma unroll
        for (int r = 0; r < 4; ++r) rsum[i][r] = 0.f;
    }
    const float* maskb = mask + b * S_;

    for (int kt = 0; kt < 16; ++kt) {
        int k0 = kt * 128;
#pragma unroll
        for (int it = 0; it < 4; ++it) {
            int e  = (it * 256 + tid) * 8;
            int kl = e >> 6;
            int c  = ((e >> 3) & 7) ^ (kl & 7);
            gld16(K + (bh * 2048 + k0 + kl) * 64 + c * 8, (char*)Ul + e * 2);
            int dl = e >> 7;
            int cp = (e >> 3) & 15;
            int c2 = (cp & 8) | ((cp ^ dl) & 7);
            gld16(Vt + (bh * 64 + dl) * 2048 + k0 + c2 * 8, (char*)Vl + e * 2);
        }
        __syncthreads();

        // S = Q K^T  (wave: 32 q-rows x 128 keys)
        floatx4 sacc[2][8];
#pragma unroll
        for (int i = 0; i < 2; ++i)
#pragma unroll
            for (int j = 0; j < 8; ++j) sacc[i][j] = (floatx4){0.f, 0.f, 0.f, 0.f};
#pragma unroll
        for (int j = 0; j < 8; ++j) {
            int kl = j * 16 + l15;
            int cp0 = (0 * 4 + quad) ^ (kl & 7);
            short8 bf0 = *(const short8*)(Ul + kl * 64 + cp0 * 8);
            int cp1 = (1 * 4 + quad) ^ (kl & 7);
            short8 bf1 = *(const short8*)(Ul + kl * 64 + cp1 * 8);
#pragma unroll
            for (int i = 0; i < 2; ++i) {
                sacc[i][j] = __builtin_amdgcn_mfma_f32_16x16x32_bf16(qf[i][0], bf0, sacc[i][j], 0, 0, 0);
                sacc[i][j] = __builtin_amdgcn_mfma_f32_16x16x32_bf16(qf[i][1], bf1, sacc[i][j], 0, 0, 0);
            }
        }
        __syncthreads();   // all waves done reading K-tile before P overwrites Ul

        // P = exp(S + mask*-1e9)
#pragma unroll
        for (int j = 0; j < 8; ++j) {
            float mv = maskb[k0 + j * 16 + l15] * (-1e9f);
#pragma unroll
            for (int i = 0; i < 2; ++i) {
                int row = wq + i * 16 + quad * 4;
#pragma unroll
                for (int r = 0; r < 4; ++r) {
                    float p = __expf(sacc[i][j][r] + mv);
                    rsum[i][r] += p;
                    Ul[(row + r) * 136 + j * 16 + l15] = f2bf(p);
                }
            }
        }
        // no barrier: each wave reads only its own P rows

        // O += P V
#pragma unroll
        for (int kk = 0; kk < 4; ++kk) {
            short8 af[2], bv4[4];
#pragma unroll
            for (int i = 0; i < 2; ++i)
                af[i] = *(const short8*)(Ul + (wq + i * 16 + l15) * 136 + kk * 32 + quad * 8);
#pragma unroll
            for (int j2 = 0; j2 < 4; ++j2) {
                int dl = j2 * 16 + l15;
                int c  = kk * 4 + quad;
                int cp = (c & 8) | ((c ^ dl) & 7);
                bv4[j2] = *(const short8*)(Vl + dl * 128 + cp * 8);
            }
#pragma unroll
            for (int i = 0; i < 2; ++i)
#pragma unroll
                for (int j2 = 0; j2 < 4; ++j2)
                    oacc[i][j2] = __builtin_amdgcn_mfma_f32_16x16x32_bf16(af[i], bv4[j2], oacc[i][j2], 0, 0, 0);
        }
        __syncthreads();
    }

#pragma unroll
    for (int i = 0; i < 2; ++i)
#pragma unroll
        for (int r = 0; r < 4; ++r) {
            float v = rsum[i][r];
            v += __shfl_xor(v, 1); v += __shfl_xor(v, 2);
            v += __shfl_xor(v, 4); v += __shfl_xor(v, 8);
            rsum[i][r] = 1.0f / v;
        }

#pragma unroll
    for (int i = 0; i < 2; ++i)
#pragma unroll
        for (int j2 = 0; j2 < 4; ++j2)
#pragma unroll
            for (int r = 0; r < 4; ++r) {
                int qrow = q0 + wq + i * 16 + quad * 4 + r;
                int hcol = nh * 64 + j2 * 16 + l15;
                Ao[(b * 2048 + qrow) * 1024 + hcol] = f2bf(oacc[i][j2][r] * rsum[i][r]);
            }
}

// ---------------------------------------------------------------------------
// 5) Output projection, double-buffered pipeline. Tile 128x128, K=1024.
// ---------------------------------------------------------------------------
__global__ __launch_bounds__(256) void k_proj_gemm(
    const unsigned short* __restrict__ A, const unsigned short* __restrict__ Wt,
    const float* __restrict__ bo, float* __restrict__ out) {
    __shared__ unsigned short Al[2][128 * 64];
    __shared__ unsigned short Bl[2][128 * 64];

    int n0 = blockIdx.x * 128, m0 = blockIdx.y * 128;
    int tid = threadIdx.x, lane = tid & 63, w = tid >> 6;
    int quad = lane >> 4, l15 = lane & 15;
    int wm = w >> 1, wn = w & 1;

    floatx4 acc[4][4];
#pragma unroll
    for (int i = 0; i < 4; ++i)
#pragma unroll
        for (int j = 0; j < 4; ++j) acc[i][j] = (floatx4){0.f, 0.f, 0.f, 0.f};

    int eoff[4], aoff[4], boff[4];
#pragma unroll
    for (int it = 0; it < 4; ++it) {
        int e  = (it * 256 + tid) * 8;
        int rl = e >> 6;
        int c  = ((e >> 3) & 7) ^ (rl & 7);
        eoff[it] = e;
        aoff[it] = (m0 + rl) * 1024 + c * 8;
        boff[it] = (n0 + rl) * 1024 + c * 8;
    }

    auto stage = [&](int buf, int k0) {
#pragma unroll
        for (int it = 0; it < 4; ++it) {
            gld16(A + aoff[it] + k0, (char*)Al[buf] + eoff[it] * 2);
            gld16(Wt + boff[it] + k0, (char*)Bl[buf] + eoff[it] * 2);
        }
    };
    auto compute = [&](int buf) {
#pragma unroll
        for (int kk = 0; kk < 2; ++kk) {
            short8 af[4], bf[4];
#pragma unroll
            for (int i = 0; i < 4; ++i) {
                int m  = wm * 64 + i * 16 + l15;
                int cp = (kk * 4 + quad) ^ (m & 7);
                af[i]  = *(const short8*)(Al[buf] + m * 64 + cp * 8);
            }
#pragma unroll
            for (int j = 0; j < 4; ++j) {
                int n  = wn * 64 + j * 16 + l15;
                int cp = (kk * 4 + quad) ^ (n & 7);
                bf[j]  = *(const short8*)(Bl[buf] + n * 64 + cp * 8);
            }
#pragma unroll
            for (int i = 0; i < 4; ++i)
#pragma unroll
                for (int j = 0; j < 4; ++j)
                    acc[i][j] = __builtin_amdgcn_mfma_f32_16x16x32_bf16(af[i], bf[j], acc[i][j], 0, 0, 0);
        }
    };

    stage(0, 0);
    __syncthreads();
    for (int kt = 0; kt < 16; kt += 2) {
        if (kt + 1 < 16) stage(1, (kt + 1) * 64);
        compute(0);
        __syncthreads();
        if (kt + 2 < 16) stage(0, (kt + 2) * 64);
        compute(1);
        __syncthreads();
    }

#pragma unroll
    for (int j = 0; j < 4; ++j) {
        int n = n0 + wn * 64 + j * 16 + l15;
        float bb = bo[n];
#pragma unroll
        for (int i = 0; i < 4; ++i) {
            int m = m0 + wm * 64 + i * 16 + quad * 4;
#pragma unroll
            for (int r = 0; r < 4; ++r)
                out[(m + r) * 1024 + n] = acc[i][j][r] + bb;
        }
    }
}

// ---------------------------------------------------------------------------
extern "C" void kernel_launch(void* const* d_in, const int* in_sizes, int n_in,
                              void* d_out, int out_size, void* d_ws, size_t ws_size,
                              hipStream_t stream) {
    (void)in_sizes; (void)n_in; (void)out_size; (void)ws_size;
    const float* q_in = (const float*)d_in[0];
    const float* s_in = (const float*)d_in[1];
    const float* mask = (const float*)d_in[2];
    const float* Wq   = (const float*)d_in[3];
    const float* bq   = (const float*)d_in[4];
    const float* Wk   = (const float*)d_in[5];
    const float* bk   = (const float*)d_in[6];
    const float* Wv   = (const float*)d_in[7];
    const float* bv   = (const float*)d_in[8];
    const float* Wo   = (const float*)d_in[9];
    const float* bo   = (const float*)d_in[10];
    float* out = (float*)d_out;

    char* ws = (char*)d_ws;
    size_t off = 0;
    auto alloc = [&](size_t bytes) {
        char* p = ws + off;
        off += (bytes + 255) & ~(size_t)255;
        return p;
    };
    unsigned short* xqp = (unsigned short*)alloc((size_t)B_ * 2050 * 1024 * 2);
    unsigned short* xsp = (unsigned short*)alloc((size_t)B_ * 2050 * 1024 * 2);
    unsigned short* Wqt = (unsigned short*)alloc((size_t)KC_ * H_ * 2);
    unsigned short* Wkt = (unsigned short*)alloc((size_t)KC_ * H_ * 2);
    unsigned short* Wvt = (unsigned short*)alloc((size_t)KC_ * H_ * 2);
    unsigned short* Wot = (unsigned short*)alloc((size_t)H_ * H_ * 2);
    unsigned short* Qb  = (unsigned short*)alloc((size_t)B_ * NH_ * S_ * D_ * 2);
    unsigned short* Kb  = (unsigned short*)alloc((size_t)B_ * NH_ * S_ * D_ * 2);
    unsigned short* Vtb = (unsigned short*)alloc((size_t)B_ * NH_ * S_ * D_ * 2);
    unsigned short* Ab  = (unsigned short*)alloc((size_t)B_ * S_ * H_ * 2);

    k_pad_convert<<<4100, 256, 0, stream>>>(q_in, xqp);
    k_pad_convert<<<4100, 256, 0, stream>>>(s_in, xsp);
    k_transpose_bf16<<<dim3(32, 96), dim3(32, 8), 0, stream>>>(Wq, Wqt, KC_, H_);
    k_transpose_bf16<<<dim3(32, 96), dim3(32, 8), 0, stream>>>(Wk, Wkt, KC_, H_);
    k_transpose_bf16<<<dim3(32, 96), dim3(32, 8), 0, stream>>>(Wv, Wvt, KC_, H_);
    k_transpose_bf16<<<dim3(32, 32), dim3(32, 8), 0, stream>>>(Wo, Wot, H_, H_);
    k_conv_gemm<<<dim3(8, 32, 3), 256, 0, stream>>>(xqp, xsp, Wqt, Wkt, Wvt,
                                                    bq, bk, bv, Qb, Kb, Vtb);
    k_flash<<<dim3(16, 32), 256, 0, stream>>>(Qb, Kb, Vtb, mask, Ab);
    k_proj_gemm<<<dim3(8, 32), 256, 0, stream>>>(Ab, Wot, bo, out);
}